// Round 5
// baseline (3476.339 us; speedup 1.0000x reference)
//
#include <hip/hip_runtime.h>
#include <hip/hip_bf16.h>

#define BB 32
#define WW 384
#define LL 512
#define ITERS 16
#define NPB (WW * LL)
#define LROWS 514           // 1 + 512 + 1 halo rows
#define CIP 416             // padded ci for it buffers (13 K-chunks of 32)

typedef __attribute__((ext_vector_type(8))) short bf16x8;
typedef __attribute__((ext_vector_type(4))) float f32x4;

__device__ __forceinline__ float b2f(short s) {
    unsigned u = ((unsigned)(unsigned short)s) << 16;
    float f;
    __builtin_memcpy(&f, &u, 4);
    return f;
}

__device__ __forceinline__ void gload_lds16(const void* g, void* l) {
    __builtin_amdgcn_global_load_lds(
        (const __attribute__((address_space(1))) void*)g,
        (__attribute__((address_space(3))) void*)l, 16, 0, 0);
}

// ---------------------------------------------------------------- prep
__global__ void wsplit_op(const float* __restrict__ w, short* __restrict__ wh,
                          short* __restrict__ wl) {
    int i = blockIdx.x * 256 + threadIdx.x;
    if (i >= 3 * 384 * CIP) return;
    int ci = i % CIP, co = (i / CIP) % 384, tap = i / (CIP * 384);
    float v = (ci < 385) ? w[(co * 385 + ci) * 3 + tap] : 0.f;
    __hip_bfloat16 h = __float2bfloat16(v);
    float lo = v - __bfloat162float(h);
    ((__hip_bfloat16*)wh)[i] = h;
    ((__hip_bfloat16*)wl)[i] = __float2bfloat16(lo);
}

__global__ void wsplit_h(const float* __restrict__ w, short* __restrict__ wh,
                         int COD, int CIN, int CO_real) {
    int i = blockIdx.x * 256 + threadIdx.x;
    if (i >= 3 * COD * CIN) return;
    int ci = i % CIN, co = (i / CIN) % COD, tap = i / (CIN * COD);
    float v = (co < CO_real) ? w[(co * CIN + ci) * 3 + tap] : 0.f;
    ((__hip_bfloat16*)wh)[i] = __float2bfloat16(v);
}

// zero halo rows of it buffers + a1 + a2; write x (hi/lo) into channel 384
// of both it ping-pong buffers, zero channels 385..415 (interior rows).
__global__ void init_rows(const float* __restrict__ x, short* itAh, short* itAl,
                          short* itBh, short* itBl, short* a1, short* a2) {
    int row = blockIdx.x % LROWS, b = blockIdx.x / LROWS;
    int tid = threadIdx.x;
    size_t base = ((size_t)b * LROWS + row) * CIP;
    size_t base1 = ((size_t)b * LROWS + row) * WW;
    size_t base2 = ((size_t)b * LROWS + row) * 192;
    if (row == 0 || row == LROWS - 1) {
        for (int i = tid; i < CIP; i += 64) {
            itAh[base + i] = 0; itAl[base + i] = 0;
            itBh[base + i] = 0; itBl[base + i] = 0;
        }
        for (int i = tid; i < WW; i += 64) a1[base1 + i] = 0;
        for (int i = tid; i < 192; i += 64) a2[base2 + i] = 0;
    } else {
        if (tid < 32) {
            int ci = WW + tid;
            short h = 0, l = 0;
            if (ci == WW) {
                float xv = x[b * LL + row - 1];
                __hip_bfloat16 xh = __float2bfloat16(xv);
                float xlo = xv - __bfloat162float(xh);
                h = *(short*)&xh;
                __hip_bfloat16 xl2 = __float2bfloat16(xlo);
                l = *(short*)&xl2;
            }
            itAh[base + ci] = h; itAl[base + ci] = l;
            itBh[base + ci] = h; itBl[base + ci] = l;
        }
    }
}

__global__ void zero_part(float* part, int n) {
    int i = blockIdx.x * 256 + threadIdx.x;
    if (i < n) part[i] = 0.f;
}

// it0 = relu(conv1d(x, proj_w)) + LN stats. 256 blocks -> 8 atomics/address.
__global__ __launch_bounds__(256) void proj_relu(const float* __restrict__ x,
                                                 const float* __restrict__ wp,
                                                 short* __restrict__ oh,
                                                 short* __restrict__ ol,
                                                 float* __restrict__ part) {
    int b = blockIdx.x >> 3, sl = blockIdx.x & 7;
    int tid = threadIdx.x;
    __shared__ float ws[WW * 3];
    __shared__ float xs[66];
    for (int i = tid; i < WW * 3; i += 256) ws[i] = wp[i];
    int l0 = sl * 64;
    for (int i = tid; i < 66; i += 256) {
        int l = l0 + i - 1;
        xs[i] = (l >= 0 && l < LL) ? x[b * LL + l] : 0.f;
    }
    __syncthreads();
    float s = 0.f, sq = 0.f;
    for (int idx = tid; idx < 64 * WW; idx += 256) {
        int lo = idx / WW, co = idx % WW;
        float v = fmaxf(ws[co * 3] * xs[lo] + ws[co * 3 + 1] * xs[lo + 1] +
                            ws[co * 3 + 2] * xs[lo + 2], 0.f);
        size_t o = ((size_t)b * LROWS + l0 + lo + 1) * CIP + co;
        __hip_bfloat16 h = __float2bfloat16(v);
        float lof = v - __bfloat162float(h);
        oh[o] = *(short*)&h;
        __hip_bfloat16 l2 = __float2bfloat16(lof);
        ol[o] = *(short*)&l2;
        s += v; sq += v * v;
    }
    #pragma unroll
    for (int off = 32; off > 0; off >>= 1) {
        s += __shfl_down(s, off);
        sq += __shfl_down(sq, off);
    }
    __shared__ float sr[8];
    int w = tid >> 6;
    if ((tid & 63) == 0) { sr[w] = s; sr[4 + w] = sq; }
    __syncthreads();
    if (tid == 0) {
        atomicAdd(&part[b * 2], sr[0] + sr[1] + sr[2] + sr[3]);
        atomicAdd(&part[b * 2 + 1], sr[4] + sr[5] + sr[6] + sr[7]);
    }
}

// ------------------------------------------------- MFMA implicit-GEMM conv
// Block: 4 waves (256 thr), tile (4*MT*16)l x 64co; wave tile MT*16 x 64.
// Grid swizzle: bid = ct*GROUPS + g, GROUPS = BB*LT = 0 mod 8, so all ct's
// sharing one A-tile land on the same XCD (bid%8 == g%8) -> L2 A reuse.
// A-tile (hi[/lo]) staged in LDS via global_load_lds (width 16).
// MODE 0: relu -> bf16 channel-last out (stride OST, interior rows).
// MODE 1: energy epilogue: xl=LN(in), nv=xl-0.1c-0.2relu(xl) -> hi/lo + stats.
template <int CHUNKS, int ICIP, int WCI, int COD, int CT, int MT, int MODE,
          bool SPLIT, int OST>
__global__ __launch_bounds__(256) void mfma_conv(
    const short* __restrict__ inh, const short* __restrict__ inl,
    const short* __restrict__ wh, const short* __restrict__ wl,
    const float* __restrict__ part_in, float* __restrict__ part_out,
    short* __restrict__ outh, short* __restrict__ outl) {
    constexpr int NW = 4;               // waves per block
    constexpr int BM = NW * MT * 16;    // block l-tile
    constexpr int LT = 512 / BM;
    constexpr int GROUPS = BB * LT;     // blocks sharing nothing but W
    constexpr int R = BM + 2;           // staged rows (tile + 2 halo)
    constexpr int RA = BM + 4;          // allocated rows per section
    constexpr int SEC = RA * 8;         // section stride in shorts (16 B/row)
    constexpr int NS = SPLIT ? 8 : 4;   // sections (4 ci-octets x hi/lo)
    constexpr int NI = (R + 63) / 64;   // staging insts per section

    int bid = blockIdx.x;
    int g = bid % GROUPS;
    int ct = bid / GROUPS;
    int b = g / LT;
    int lt = g % LT;
    int l0 = lt * BM, co0 = ct * 64;
    int tid = threadIdx.x;
    int lane = tid & 63, w = tid >> 6;
    int lane15 = lane & 15, q = lane >> 4;
    int wmbase = w * MT * 16;
    const size_t rowbase = (size_t)b * LROWS + l0;

    __shared__ short As[NS * SEC];

    f32x4 acc[MT][4];
    #pragma unroll
    for (int i = 0; i < MT; i++)
        #pragma unroll
        for (int j = 0; j < 4; j++) acc[i][j] = (f32x4){0.f, 0.f, 0.f, 0.f};

    for (int kc = 0; kc < CHUNKS; kc++) {
        int ci0 = kc * 32;
        // ---- stage A chunk into LDS (waves split the NS*NI insts)
        for (int item = w; item < NS * NI; item += NW) {
            int s = item / NI, i = item % NI;
            int qq = s & 3;
            const short* src = (SPLIT && (s >> 2)) ? inl : inh;
            int row = i * 64 + lane;
            if (row < R)
                gload_lds16(src + (rowbase + row) * ICIP + ci0 + qq * 8,
                            &As[s * SEC + i * 64 * 8]);
        }
        __syncthreads();
        #pragma unroll
        for (int tap = 0; tap < 3; tap++) {
            bf16x8 ah[MT], al[MT], bh[4], bl[4];
            #pragma unroll
            for (int mt = 0; mt < MT; mt++) {
                int row = wmbase + mt * 16 + lane15 + tap;
                const short* ap = &As[q * SEC + row * 8];
                ah[mt] = *(const bf16x8*)ap;
                if (SPLIT) al[mt] = *(const bf16x8*)(ap + 4 * SEC);
            }
            #pragma unroll
            for (int nt = 0; nt < 4; nt++) {
                size_t bo = ((size_t)(tap * COD + co0 + nt * 16 + lane15)) * WCI +
                            ci0 + q * 8;
                bh[nt] = *(const bf16x8*)(wh + bo);
                if (SPLIT) bl[nt] = *(const bf16x8*)(wl + bo);
            }
            #pragma unroll
            for (int mt = 0; mt < MT; mt++)
                #pragma unroll
                for (int nt = 0; nt < 4; nt++) {
                    acc[mt][nt] = __builtin_amdgcn_mfma_f32_16x16x32_bf16(
                        ah[mt], bh[nt], acc[mt][nt], 0, 0, 0);
                    if (SPLIT) {
                        acc[mt][nt] = __builtin_amdgcn_mfma_f32_16x16x32_bf16(
                            ah[mt], bl[nt], acc[mt][nt], 0, 0, 0);
                        acc[mt][nt] = __builtin_amdgcn_mfma_f32_16x16x32_bf16(
                            al[mt], bh[nt], acc[mt][nt], 0, 0, 0);
                    }
                }
        }
        __syncthreads();
    }

    if (MODE == 1) {
        float s_in = part_in[b * 2], sq_in = part_in[b * 2 + 1];
        float mu = s_in / (float)NPB;
        float var = sq_in / (float)NPB - mu * mu;
        float rs = rsqrtf(var + 1e-5f);
        float s = 0.f, sq = 0.f;
        #pragma unroll
        for (int mt = 0; mt < MT; mt++)
            #pragma unroll
            for (int nt = 0; nt < 4; nt++)
                #pragma unroll
                for (int r = 0; r < 4; r++) {
                    int m = wmbase + mt * 16 + q * 4 + r;
                    int n = co0 + nt * 16 + lane15;
                    size_t idx = (rowbase + m + 1) * ICIP + n;
                    float itv = b2f(inh[idx]) + b2f(inl[idx]);
                    float xl = (itv - mu) * rs;
                    float nv = xl - 0.1f * acc[mt][nt][r] - 0.2f * fmaxf(xl, 0.f);
                    s += nv;
                    sq += nv * nv;
                    __hip_bfloat16 h = __float2bfloat16(nv);
                    float lo = nv - __bfloat162float(h);
                    outh[idx] = *(short*)&h;
                    __hip_bfloat16 l2 = __float2bfloat16(lo);
                    outl[idx] = *(short*)&l2;
                }
        #pragma unroll
        for (int off = 32; off > 0; off >>= 1) {
            s += __shfl_down(s, off);
            sq += __shfl_down(sq, off);
        }
        __shared__ float sr[8];
        if (lane == 0) { sr[w] = s; sr[4 + w] = sq; }
        __syncthreads();
        if (tid == 0) {
            atomicAdd(&part_out[b * 2], sr[0] + sr[1] + sr[2] + sr[3]);
            atomicAdd(&part_out[b * 2 + 1], sr[4] + sr[5] + sr[6] + sr[7]);
        }
    } else {
        #pragma unroll
        for (int mt = 0; mt < MT; mt++)
            #pragma unroll
            for (int nt = 0; nt < 4; nt++)
                #pragma unroll
                for (int r = 0; r < 4; r++) {
                    int m = wmbase + mt * 16 + q * 4 + r;
                    int n = co0 + nt * 16 + lane15;
                    size_t idx = (rowbase + m + 1) * OST + n;
                    __hip_bfloat16 h = __float2bfloat16(fmaxf(acc[mt][nt][r], 0.f));
                    outh[idx] = *(short*)&h;
                }
    }
}

// Final 192->2 conv from a2 [32][514][192] bf16 channel-last (halo-padded).
__global__ __launch_bounds__(128) void h3_conv(const short* __restrict__ a2,
                                               const float* __restrict__ w3,
                                               float* __restrict__ out, int t) {
    __shared__ float ws3[2 * 192 * 3];
    int tid = threadIdx.x;
    for (int i = tid; i < 2 * 192 * 3; i += 128) ws3[i] = w3[i];
    __syncthreads();
    int b = blockIdx.x >> 3, sl = blockIdx.x & 7;
    int l = sl * 64 + (tid >> 1);
    int ch = tid & 1;
    const short* r0 = a2 + ((size_t)b * LROWS + l) * 192;  // buffer row l = l-1
    const float* wc = ws3 + ch * 576;
    float a = 0.f;
    #pragma unroll 4
    for (int c8 = 0; c8 < 24; c8++) {
        bf16x8 v0 = *(const bf16x8*)(r0 + c8 * 8);
        bf16x8 v1 = *(const bf16x8*)(r0 + 192 + c8 * 8);
        bf16x8 v2 = *(const bf16x8*)(r0 + 384 + c8 * 8);
        #pragma unroll
        for (int j = 0; j < 8; j++) {
            const float* wp = wc + (c8 * 8 + j) * 3;
            a += wp[0] * b2f(v0[j]) + wp[1] * b2f(v1[j]) + wp[2] * b2f(v2[j]);
        }
    }
    out[(((size_t)b * ITERS + t) * 2 + ch) * LL + l] = a;
}

extern "C" void kernel_launch(void* const* d_in, const int* in_sizes, int n_in,
                              void* d_out, int out_size, void* d_ws, size_t ws_size,
                              hipStream_t stream) {
    const float* x = (const float*)d_in[0];
    const float* proj_w = (const float*)d_in[2];
    const float* op_w = (const float*)d_in[3];
    const float* h1_w = (const float*)d_in[4];
    const float* h2_w = (const float*)d_in[5];
    const float* h3_w = (const float*)d_in[6];
    float* out = (float*)d_out;

    char* base = (char*)d_ws;
    size_t off = 0;
    auto alloc = [&](size_t bytes) {
        char* p = base + off;
        off += (bytes + 255) & ~(size_t)255;
        return p;
    };
    const size_t ITB = (size_t)BB * LROWS * CIP * 2;
    short* itAh = (short*)alloc(ITB);
    short* itAl = (short*)alloc(ITB);
    short* itBh = (short*)alloc(ITB);
    short* itBl = (short*)alloc(ITB);
    short* a1 = (short*)alloc((size_t)BB * LROWS * WW * 2);
    short* a2 = (short*)alloc((size_t)BB * LROWS * 192 * 2);
    short* wOph = (short*)alloc((size_t)3 * 384 * CIP * 2);
    short* wOpl = (short*)alloc((size_t)3 * 384 * CIP * 2);
    short* wH1 = (short*)alloc((size_t)3 * 384 * 384 * 2);
    short* wH2 = (short*)alloc((size_t)3 * 256 * 384 * 2);
    float* part = (float*)alloc((size_t)(ITERS + 1) * 64 * 4);
    if (off > ws_size) return;

    wsplit_op<<<(3 * 384 * CIP + 255) / 256, 256, 0, stream>>>(op_w, wOph, wOpl);
    wsplit_h<<<(3 * 384 * 384 + 255) / 256, 256, 0, stream>>>(h1_w, wH1, 384, 384, 384);
    wsplit_h<<<(3 * 256 * 384 + 255) / 256, 256, 0, stream>>>(h2_w, wH2, 256, 384, 192);
    init_rows<<<BB * LROWS, 64, 0, stream>>>(x, itAh, itAl, itBh, itBl, a1, a2);
    zero_part<<<5, 256, 0, stream>>>(part, (ITERS + 1) * 64);
    proj_relu<<<BB * 8, 256, 0, stream>>>(x, proj_w, itAh, itAl, part);

    short *ch = itAh, *cl = itAl, *nh = itBh, *nl = itBl;
    for (int t = 0; t < ITERS; t++) {
        // op conv (split, energy epilogue): cur -> nxt, stats -> part[t+1]
        // 4 waves/block, MT=2 -> BM=128, LT=4, GROUPS=128, grid=768 (3/CU)
        mfma_conv<13, CIP, CIP, 384, 6, 2, 1, true, CIP>
            <<<768, 256, 0, stream>>>(ch, cl, wOph, wOpl, part + t * 64,
                                      part + (t + 1) * 64, nh, nl);
        // h1: nxt_hi -> a1 (bf16 channel-last, relu)
        mfma_conv<12, CIP, 384, 384, 6, 2, 0, false, WW>
            <<<768, 256, 0, stream>>>(nh, nullptr, wH1, nullptr, nullptr,
                                      nullptr, a1, nullptr);
        // h2: a1 -> a2 (bf16 channel-last, relu); MT=1 -> BM=64, LT=8, grid=768
        mfma_conv<12, WW, 384, 256, 3, 1, 0, false, 192>
            <<<768, 256, 0, stream>>>(a1, nullptr, wH2, nullptr, nullptr,
                                      nullptr, a2, nullptr);
        h3_conv<<<BB * 8, 128, 0, stream>>>(a2, h3_w, out, t);
        short* th = ch; ch = nh; nh = th;
        short* tl = cl; cl = nl; nl = tl;
    }
}

// Round 6
// 2120.973 us; speedup vs baseline: 1.6390x; 1.6390x over previous
//
#include <hip/hip_runtime.h>
#include <hip/hip_bf16.h>

#define BB 32
#define WW 384
#define LL 512
#define ITERS 16
#define NPB (WW * LL)
#define LROWS 514            // 1 + 512 + 1 halo rows
#define RP (LROWS * 8)       // shorts per octet-plane (4112)

typedef __attribute__((ext_vector_type(8))) short bf16x8;
typedef __attribute__((ext_vector_type(4))) float f32x4;

__device__ __forceinline__ float b2f(short s) {
    unsigned u = ((unsigned)(unsigned short)s) << 16;
    float f;
    __builtin_memcpy(&f, &u, 4);
    return f;
}
__device__ __forceinline__ short f2b(float v) {
    __hip_bfloat16 h = __float2bfloat16(v);
    return *(short*)&h;
}

// ---------------------------------------------------------------- prep
// op_w [384(co)][385(ci)][3] f32 -> Wh/Wl [3][52][384][8] bf16 hi/lo
__global__ void wsplit_op(const float* __restrict__ w, short* __restrict__ wh,
                          short* __restrict__ wl) {
    int i = blockIdx.x * 256 + threadIdx.x;
    if (i >= 3 * 52 * 384 * 8) return;
    int e = i & 7, co = (i >> 3) % 384, oct = (i >> 3) / 384 % 52,
        tap = i / (8 * 384 * 52);
    int ci = oct * 8 + e;
    float v = (ci < 385) ? w[(co * 385 + ci) * 3 + tap] : 0.f;
    __hip_bfloat16 h = __float2bfloat16(v);
    wh[i] = *(short*)&h;
    wl[i] = f2b(v - __bfloat162float(h));
}

// src [CO_real][384(ci)][3] f32 -> dst [3][48][COD][8] bf16 (co>=CO_real -> 0)
__global__ void wsplit_h(const float* __restrict__ w, short* __restrict__ wh,
                         int COD, int CO_real) {
    int i = blockIdx.x * 256 + threadIdx.x;
    if (i >= 3 * 48 * COD * 8) return;
    int e = i & 7, co = (i >> 3) % COD, oct = (i >> 3) / COD % 48,
        tap = i / (8 * COD * 48);
    int ci = oct * 8 + e;
    float v = (co < CO_real) ? w[(co * 384 + ci) * 3 + tap] : 0.f;
    wh[i] = f2b(v);
}

// Zero halo rows (all buffers), install x channel (octet 48, elem 0) + zero
// pad octets 48..51 in both state ping-pong buffers.
__global__ void init_rows(const float* __restrict__ x, short* itAh, short* itAl,
                          short* itBh, short* itBl, short* a1, short* a2) {
    int row = blockIdx.x % LROWS, b = blockIdx.x / LROWS;
    int tid = threadIdx.x;
    size_t sb = (size_t)b * 52 * RP;
    if (row == 0 || row == LROWS - 1) {
        for (int i = tid; i < 52 * 8; i += 64) {
            size_t o = sb + (size_t)(i >> 3) * RP + row * 8 + (i & 7);
            itAh[o] = 0; itAl[o] = 0; itBh[o] = 0; itBl[o] = 0;
        }
        for (int i = tid; i < 48 * 8; i += 64)
            a1[(size_t)b * 48 * RP + (size_t)(i >> 3) * RP + row * 8 + (i & 7)] = 0;
        for (int i = tid; i < 32 * 8; i += 64)
            a2[(size_t)b * 32 * RP + (size_t)(i >> 3) * RP + row * 8 + (i & 7)] = 0;
    } else if (tid < 32) {
        int oct = 48 + (tid >> 3), e = tid & 7;
        short h = 0, l = 0;
        if (oct == 48 && e == 0) {
            float xv = x[b * LL + row - 1];
            __hip_bfloat16 xh = __float2bfloat16(xv);
            h = *(short*)&xh;
            l = f2b(xv - __bfloat162float(xh));
        }
        size_t o = sb + (size_t)oct * RP + row * 8 + e;
        itAh[o] = h; itAl[o] = l; itBh[o] = h; itBl[o] = l;
    }
}

__global__ void zero_part(float* part, int n) {
    int i = blockIdx.x * 256 + threadIdx.x;
    if (i < n) part[i] = 0.f;
}

// it0 = relu(conv1d(x, proj_w)) -> octet-planar hi/lo + LN stats.
__global__ __launch_bounds__(256) void proj_relu(const float* __restrict__ x,
                                                 const float* __restrict__ wp,
                                                 short* __restrict__ oh,
                                                 short* __restrict__ ol,
                                                 float* __restrict__ part) {
    int b = blockIdx.x >> 3, sl = blockIdx.x & 7;
    int tid = threadIdx.x;
    __shared__ float ws[WW * 3];
    __shared__ float xs[66];
    for (int i = tid; i < WW * 3; i += 256) ws[i] = wp[i];
    int l0 = sl * 64;
    for (int i = tid; i < 66; i += 256) {
        int l = l0 + i - 1;
        xs[i] = (l >= 0 && l < LL) ? x[b * LL + l] : 0.f;
    }
    __syncthreads();
    size_t sb = (size_t)b * 52 * RP;
    float s = 0.f, sq = 0.f;
    for (int idx = tid; idx < 64 * WW; idx += 256) {
        int lo = idx / WW, co = idx % WW;
        float v = fmaxf(ws[co * 3] * xs[lo] + ws[co * 3 + 1] * xs[lo + 1] +
                            ws[co * 3 + 2] * xs[lo + 2], 0.f);
        size_t o = sb + (size_t)(co >> 3) * RP + (l0 + lo + 1) * 8 + (co & 7);
        __hip_bfloat16 h = __float2bfloat16(v);
        oh[o] = *(short*)&h;
        ol[o] = f2b(v - __bfloat162float(h));
        s += v; sq += v * v;
    }
    #pragma unroll
    for (int off = 32; off > 0; off >>= 1) {
        s += __shfl_down(s, off);
        sq += __shfl_down(sq, off);
    }
    __shared__ float sr[8];
    int w = tid >> 6;
    if ((tid & 63) == 0) { sr[w] = s; sr[4 + w] = sq; }
    __syncthreads();
    if (tid == 0) {
        atomicAdd(&part[b * 2], sr[0] + sr[1] + sr[2] + sr[3]);
        atomicAdd(&part[b * 2 + 1], sr[4] + sr[5] + sr[6] + sr[7]);
    }
}

// ------------------------------------------------- MFMA implicit-GEMM conv
// Direct-global dataflow: NO LDS staging, NO barriers in the K-loop.
// Input octet-planar [IOCT][514][8]; weights [3][CHUNKS*4][COD][8]; all
// fragment loads are contiguous 256B segments per 16-lane group.
// Block: 2 waves splitting co; wave tile 64l x 64co (4x4 16x16x32 MFMA).
// Grid: CT*256, g=bid&255 (b*8+lt), ct=bid>>8 -> A-sharing blocks on same XCD.
// MODE 0: relu -> bf16 octet-planar out. MODE 1: energy epilogue + LN stats.
template <int CHUNKS, int IOCT, int OOCT, int COD, int MODE, bool SPLIT>
__global__ __launch_bounds__(128) void mfma_conv(
    const short* __restrict__ inh, const short* __restrict__ inl,
    const short* __restrict__ wh, const short* __restrict__ wl,
    const float* __restrict__ part_in, float* __restrict__ part_out,
    short* __restrict__ outh, short* __restrict__ outl) {
    int bid = blockIdx.x;
    int g = bid & 255;
    int ct = bid >> 8;
    int b = g >> 3, lt = g & 7;
    int l0 = lt * 64;
    int tid = threadIdx.x;
    int lane = tid & 63;
    int wn = __builtin_amdgcn_readfirstlane(tid >> 6);
    int lane15 = lane & 15, q = lane >> 4;
    int co0 = ct * 128 + wn * 64;
    const size_t ibase = (size_t)b * IOCT * RP;

    f32x4 acc[4][4];
    #pragma unroll
    for (int i = 0; i < 4; i++)
        #pragma unroll
        for (int j = 0; j < 4; j++) acc[i][j] = (f32x4){0.f, 0.f, 0.f, 0.f};

    // lane-invariant bases
    const size_t arow = ibase + (size_t)q * RP + (l0 + lane15) * 8;
    const size_t brow = ((size_t)q * COD + co0 + lane15) * 8;

    #pragma unroll 1
    for (int kc = 0; kc < CHUNKS; kc++) {
        #pragma unroll
        for (int tap = 0; tap < 3; tap++) {
            bf16x8 ah[4], al[4], bh[4], bl[4];
            #pragma unroll
            for (int mt = 0; mt < 4; mt++) {
                size_t ao = arow + (size_t)kc * 4 * RP + (mt * 16 + tap) * 8;
                ah[mt] = *(const bf16x8*)(inh + ao);
                if (SPLIT) al[mt] = *(const bf16x8*)(inl + ao);
            }
            #pragma unroll
            for (int nt = 0; nt < 4; nt++) {
                size_t bo = brow + ((size_t)(tap * CHUNKS + kc) * 4) * COD * 8 +
                            nt * 16 * 8;
                bh[nt] = *(const bf16x8*)(wh + bo);
                if (SPLIT) bl[nt] = *(const bf16x8*)(wl + bo);
            }
            #pragma unroll
            for (int mt = 0; mt < 4; mt++)
                #pragma unroll
                for (int nt = 0; nt < 4; nt++) {
                    acc[mt][nt] = __builtin_amdgcn_mfma_f32_16x16x32_bf16(
                        ah[mt], bh[nt], acc[mt][nt], 0, 0, 0);
                    if (SPLIT) {
                        acc[mt][nt] = __builtin_amdgcn_mfma_f32_16x16x32_bf16(
                            ah[mt], bl[nt], acc[mt][nt], 0, 0, 0);
                        acc[mt][nt] = __builtin_amdgcn_mfma_f32_16x16x32_bf16(
                            al[mt], bh[nt], acc[mt][nt], 0, 0, 0);
                    }
                }
        }
    }

    const size_t obase = (size_t)b * OOCT * RP;
    if (MODE == 1) {
        float s_in = part_in[b * 2], sq_in = part_in[b * 2 + 1];
        float mu = s_in / (float)NPB;
        float var = sq_in / (float)NPB - mu * mu;
        float rs = rsqrtf(var + 1e-5f);
        float s = 0.f, sq = 0.f;
        #pragma unroll
        for (int mt = 0; mt < 4; mt++)
            #pragma unroll
            for (int nt = 0; nt < 4; nt++)
                #pragma unroll
                for (int r = 0; r < 4; r++) {
                    int m = mt * 16 + q * 4 + r;
                    int n = co0 + nt * 16 + lane15;
                    size_t idx = ibase + (size_t)(n >> 3) * RP +
                                 (l0 + m + 1) * 8 + (n & 7);
                    float itv = b2f(inh[idx]) + b2f(inl[idx]);
                    float xl = (itv - mu) * rs;
                    float nv = xl - 0.1f * acc[mt][nt][r] - 0.2f * fmaxf(xl, 0.f);
                    s += nv;
                    sq += nv * nv;
                    __hip_bfloat16 h = __float2bfloat16(nv);
                    outh[idx] = *(short*)&h;
                    outl[idx] = f2b(nv - __bfloat162float(h));
                }
        #pragma unroll
        for (int off = 32; off > 0; off >>= 1) {
            s += __shfl_down(s, off);
            sq += __shfl_down(sq, off);
        }
        __shared__ float sr[4];
        int w = tid >> 6;
        if (lane == 0) { sr[w] = s; sr[2 + w] = sq; }
        __syncthreads();
        if (tid == 0) {
            atomicAdd(&part_out[b * 2], sr[0] + sr[1]);
            atomicAdd(&part_out[b * 2 + 1], sr[2] + sr[3]);
        }
    } else {
        #pragma unroll
        for (int mt = 0; mt < 4; mt++)
            #pragma unroll
            for (int nt = 0; nt < 4; nt++)
                #pragma unroll
                for (int r = 0; r < 4; r++) {
                    int m = mt * 16 + q * 4 + r;
                    int n = co0 + nt * 16 + lane15;
                    size_t idx = obase + (size_t)(n >> 3) * RP +
                                 (l0 + m + 1) * 8 + (n & 7);
                    outh[idx] = f2b(fmaxf(acc[mt][nt][r], 0.f));
                }
    }
}

// Final 192->2 conv from a2 [32][32oct][514][8] bf16 octet-planar.
__global__ __launch_bounds__(128) void h3_conv(const short* __restrict__ a2,
                                               const float* __restrict__ w3,
                                               float* __restrict__ out, int t) {
    __shared__ float ws3[2 * 192 * 3];
    int tid = threadIdx.x;
    for (int i = tid; i < 2 * 192 * 3; i += 128) ws3[i] = w3[i];
    __syncthreads();
    int b = blockIdx.x >> 3, sl = blockIdx.x & 7;
    int l = sl * 64 + (tid >> 1);
    int ch = tid & 1;
    const short* ab = a2 + (size_t)b * 32 * RP;
    const float* wc = ws3 + ch * 576;
    float a = 0.f;
    #pragma unroll 4
    for (int oct = 0; oct < 24; oct++) {
        const short* p = ab + (size_t)oct * RP + l * 8;  // row l = seq l-1
        bf16x8 v0 = *(const bf16x8*)p;
        bf16x8 v1 = *(const bf16x8*)(p + 8);
        bf16x8 v2 = *(const bf16x8*)(p + 16);
        #pragma unroll
        for (int j = 0; j < 8; j++) {
            const float* wp = wc + (oct * 8 + j) * 3;
            a += wp[0] * b2f(v0[j]) + wp[1] * b2f(v1[j]) + wp[2] * b2f(v2[j]);
        }
    }
    out[(((size_t)b * ITERS + t) * 2 + ch) * LL + l] = a;
}

extern "C" void kernel_launch(void* const* d_in, const int* in_sizes, int n_in,
                              void* d_out, int out_size, void* d_ws, size_t ws_size,
                              hipStream_t stream) {
    const float* x = (const float*)d_in[0];
    const float* proj_w = (const float*)d_in[2];
    const float* op_w = (const float*)d_in[3];
    const float* h1_w = (const float*)d_in[4];
    const float* h2_w = (const float*)d_in[5];
    const float* h3_w = (const float*)d_in[6];
    float* out = (float*)d_out;

    char* base = (char*)d_ws;
    size_t off = 0;
    auto alloc = [&](size_t bytes) {
        char* p = base + off;
        off += (bytes + 255) & ~(size_t)255;
        return p;
    };
    const size_t ITB = (size_t)BB * 52 * RP * 2;  // state buffer bytes
    short* itAh = (short*)alloc(ITB);
    short* itAl = (short*)alloc(ITB);
    short* itBh = (short*)alloc(ITB);
    short* itBl = (short*)alloc(ITB);
    short* a1 = (short*)alloc((size_t)BB * 48 * RP * 2);
    short* a2 = (short*)alloc((size_t)BB * 32 * RP * 2);
    short* wOph = (short*)alloc((size_t)3 * 52 * 384 * 8 * 2);
    short* wOpl = (short*)alloc((size_t)3 * 52 * 384 * 8 * 2);
    short* wH1 = (short*)alloc((size_t)3 * 48 * 384 * 8 * 2);
    short* wH2 = (short*)alloc((size_t)3 * 48 * 256 * 8 * 2);
    float* part = (float*)alloc((size_t)(ITERS + 1) * 64 * 4);
    if (off > ws_size) return;

    wsplit_op<<<(3 * 52 * 384 * 8 + 255) / 256, 256, 0, stream>>>(op_w, wOph, wOpl);
    wsplit_h<<<(3 * 48 * 384 * 8 + 255) / 256, 256, 0, stream>>>(h1_w, wH1, 384, 384);
    wsplit_h<<<(3 * 48 * 256 * 8 + 255) / 256, 256, 0, stream>>>(h2_w, wH2, 256, 192);
    init_rows<<<BB * LROWS, 64, 0, stream>>>(x, itAh, itAl, itBh, itBl, a1, a2);
    zero_part<<<5, 256, 0, stream>>>(part, (ITERS + 1) * 64);
    proj_relu<<<BB * 8, 256, 0, stream>>>(x, proj_w, itAh, itAl, part);

    short *ch = itAh, *cl = itAl, *nh = itBh, *nl = itBl;
    for (int t = 0; t < ITERS; t++) {
        // op conv (hi/lo split, energy epilogue): cur -> nxt, stats -> part[t+1]
        mfma_conv<13, 52, 52, 384, 1, true><<<3 * 256, 128, 0, stream>>>(
            ch, cl, wOph, wOpl, part + t * 64, part + (t + 1) * 64, nh, nl);
        // h1: nxt_hi -> a1 (48 octets), relu
        mfma_conv<12, 52, 48, 384, 0, false><<<3 * 256, 128, 0, stream>>>(
            nh, nullptr, wH1, nullptr, nullptr, nullptr, a1, nullptr);
        // h2: a1 -> a2 (co padded to 256 -> 32 octets), relu
        mfma_conv<12, 48, 32, 256, 0, false><<<2 * 256, 128, 0, stream>>>(
            a1, nullptr, wH2, nullptr, nullptr, nullptr, a2, nullptr);
        h3_conv<<<BB * 8, 128, 0, stream>>>(a2, h3_w, out, t);
        short* th = ch; ch = nh; nh = th;
        short* tl = cl; cl = nl; nl = tl;
    }
}